// Round 1
// baseline (68.837 us; speedup 1.0000x reference)
//
#include <hip/hip_runtime.h>
#include <math.h>

#define N 8192
#define BS 256
#define EPSV 1e-8f

// Kernel 1: each block handles 32 consecutive i's; stages all t[] and
// exp(risk[]) into LDS (64 KB); each wave owns 8 i's in registers, lanes
// slice the j dimension (float4 granularity). Writes one partial loss per
// block: sum over its i of e_i * (risk_i - log(S_i + eps)).
__global__ __launch_bounds__(BS) void cox_partial(const float* __restrict__ risk,
                                                  const float* __restrict__ t,
                                                  const float* __restrict__ e,
                                                  float* __restrict__ blockPartial) {
    __shared__ float sT[N];
    __shared__ float sE[N];

    const int tid = threadIdx.x;

    // ---- stage t and exp(risk) into LDS, float4-vectorized ----
    const float4* t4g = (const float4*)t;
    const float4* r4g = (const float4*)risk;
    float4* sT4 = (float4*)sT;
    float4* sE4 = (float4*)sE;
    #pragma unroll
    for (int s = 0; s < N / 4 / BS; ++s) {   // 8 iterations
        int f = tid + s * BS;
        float4 tv = t4g[f];
        float4 rv = r4g[f];
        sT4[f] = tv;
        float4 ev;
        ev.x = __expf(rv.x);
        ev.y = __expf(rv.y);
        ev.z = __expf(rv.z);
        ev.w = __expf(rv.w);
        sE4[f] = ev;
    }
    __syncthreads();

    const int lane = tid & 63;
    const int wave = tid >> 6;
    const int i0 = blockIdx.x * 32 + wave * 8;   // this wave's 8 i's

    // t_i values (wave-uniform LDS broadcast reads)
    float ti[8];
    #pragma unroll
    for (int m = 0; m < 8; ++m) ti[m] = sT[i0 + m];

    float sum[8];
    #pragma unroll
    for (int m = 0; m < 8; ++m) sum[m] = 0.0f;

    // ---- main loop: 32 float4-iterations per lane covers all 8192 j ----
    #pragma unroll 2
    for (int k = 0; k < N / 4 / 64; ++k) {   // 32 iterations
        int f = lane + (k << 6);
        float4 tj = sT4[f];
        float4 ej = sE4[f];
        #pragma unroll
        for (int m = 0; m < 8; ++m) {
            float s0 = (tj.x >= ti[m]) ? ej.x : 0.0f;
            float s1 = (tj.y >= ti[m]) ? ej.y : 0.0f;
            float s2 = (tj.z >= ti[m]) ? ej.z : 0.0f;
            float s3 = (tj.w >= ti[m]) ? ej.w : 0.0f;
            sum[m] += (s0 + s1) + (s2 + s3);
        }
    }

    // ---- reduce each of the 8 sums across the 64 lanes ----
    float myS = 0.0f;
    #pragma unroll
    for (int m = 0; m < 8; ++m) {
        float v = sum[m];
        v += __shfl_xor(v, 32);
        v += __shfl_xor(v, 16);
        v += __shfl_xor(v, 8);
        v += __shfl_xor(v, 4);
        v += __shfl_xor(v, 2);
        v += __shfl_xor(v, 1);
        if (lane == m) myS = v;   // lane m keeps total S for i = i0+m
    }

    float contrib = 0.0f;
    if (lane < 8) {
        int i = i0 + lane;
        contrib = e[i] * (risk[i] - __logf(myS + EPSV));
    }

    // ---- block reduce the 32 per-i contributions (reuse sT as scratch) ----
    __syncthreads();               // all LDS reads of the main loop are done
    if (lane < 8) sT[wave * 8 + lane] = contrib;
    __syncthreads();
    if (tid == 0) {
        float tot = 0.0f;
        #pragma unroll
        for (int x = 0; x < 32; ++x) tot += sT[x];
        blockPartial[blockIdx.x] = tot;
    }
}

// Kernel 2: reduce 256 block partials -> final scalar loss.
__global__ __launch_bounds__(BS) void cox_final(const float* __restrict__ blockPartial,
                                                float* __restrict__ out) {
    const int tid = threadIdx.x;
    float v = blockPartial[tid];
    v += __shfl_xor(v, 32);
    v += __shfl_xor(v, 16);
    v += __shfl_xor(v, 8);
    v += __shfl_xor(v, 4);
    v += __shfl_xor(v, 2);
    v += __shfl_xor(v, 1);
    __shared__ float sW[4];
    if ((tid & 63) == 0) sW[tid >> 6] = v;
    __syncthreads();
    if (tid == 0) {
        float tot = sW[0] + sW[1] + sW[2] + sW[3];
        out[0] = -tot * (1.0f / (float)N);
    }
}

extern "C" void kernel_launch(void* const* d_in, const int* in_sizes, int n_in,
                              void* d_out, int out_size, void* d_ws, size_t ws_size,
                              hipStream_t stream) {
    const float* risk = (const float*)d_in[0];
    const float* t    = (const float*)d_in[1];
    const float* e    = (const float*)d_in[2];
    float* out = (float*)d_out;
    float* part = (float*)d_ws;   // 256 floats of scratch

    cox_partial<<<N / 32, BS, 0, stream>>>(risk, t, e, part);
    cox_final<<<1, BS, 0, stream>>>(part, out);
}

// Round 2
// 68.019 us; speedup vs baseline: 1.0120x; 1.0120x over previous
//
#include <hip/hip_runtime.h>
#include <math.h>

#define N 8192
#define BS 256
#define NCHUNK 4
#define CHUNK (N / NCHUNK)        // 2048 j's per block
#define EPSV 1e-8f

// Kernel 1: grid (256 i-blocks, 4 j-chunks). Each block stages its chunk's
// t[] and exp(risk[]) into LDS (16 KB -> 4+ blocks/CU, 16 waves/CU), handles
// 32 i's; each wave owns 8 i's in registers, lanes slice the chunk's j's.
// Writes partial risk-set sums Spart[chunk][i] to workspace.
__global__ __launch_bounds__(BS) void cox_partial(const float* __restrict__ risk,
                                                  const float* __restrict__ t,
                                                  float* __restrict__ Spart) {
    __shared__ float sT[CHUNK];
    __shared__ float sE[CHUNK];

    const int tid = threadIdx.x;
    const int chunk = blockIdx.y;

    // ---- stage this chunk's t and exp(risk) into LDS, float4-vectorized ----
    const float4* t4g = (const float4*)t;
    const float4* r4g = (const float4*)risk;
    float4* sT4 = (float4*)sT;
    float4* sE4 = (float4*)sE;
    #pragma unroll
    for (int s = 0; s < CHUNK / 4 / BS; ++s) {   // 2 iterations
        int fl = tid + s * BS;                   // local float4 index
        int fg = chunk * (CHUNK / 4) + fl;       // global float4 index
        float4 tv = t4g[fg];
        float4 rv = r4g[fg];
        sT4[fl] = tv;
        float4 ev;
        ev.x = __expf(rv.x);
        ev.y = __expf(rv.y);
        ev.z = __expf(rv.z);
        ev.w = __expf(rv.w);
        sE4[fl] = ev;
    }

    const int lane = tid & 63;
    const int wave = tid >> 6;
    const int i0 = blockIdx.x * 32 + wave * 8;   // this wave's 8 i's

    // t_i values from global (uniform address across lanes -> L1 broadcast)
    float ti[8];
    #pragma unroll
    for (int m = 0; m < 8; ++m) ti[m] = t[i0 + m];

    float sum[8];
    #pragma unroll
    for (int m = 0; m < 8; ++m) sum[m] = 0.0f;

    __syncthreads();

    // ---- main loop: 8 float4-iterations per lane covers the 2048-j chunk ----
    #pragma unroll
    for (int k = 0; k < CHUNK / 4 / 64; ++k) {   // 8 iterations, fully unrolled
        int f = lane + (k << 6);
        float4 tj = sT4[f];
        float4 ej = sE4[f];
        #pragma unroll
        for (int m = 0; m < 8; ++m) {
            float s0 = (tj.x >= ti[m]) ? ej.x : 0.0f;
            float s1 = (tj.y >= ti[m]) ? ej.y : 0.0f;
            float s2 = (tj.z >= ti[m]) ? ej.z : 0.0f;
            float s3 = (tj.w >= ti[m]) ? ej.w : 0.0f;
            sum[m] += (s0 + s1) + (s2 + s3);
        }
    }

    // ---- reduce each of the 8 sums across the 64 lanes ----
    float myS = 0.0f;
    #pragma unroll
    for (int m = 0; m < 8; ++m) {
        float v = sum[m];
        v += __shfl_xor(v, 32);
        v += __shfl_xor(v, 16);
        v += __shfl_xor(v, 8);
        v += __shfl_xor(v, 4);
        v += __shfl_xor(v, 2);
        v += __shfl_xor(v, 1);
        if (lane == m) myS = v;   // lane m keeps partial S for i = i0+m
    }

    if (lane < 8) {
        Spart[chunk * N + i0 + lane] = myS;
    }
}

// Kernel 2: one 1024-thread block. Combine the 4 chunk partials per i, apply
// log + event mask, reduce 8192 contributions to the scalar loss.
__global__ __launch_bounds__(1024) void cox_final(const float* __restrict__ Spart,
                                                  const float* __restrict__ risk,
                                                  const float* __restrict__ e,
                                                  float* __restrict__ out) {
    const int tid = threadIdx.x;
    const int lane = tid & 63;
    const int wave = tid >> 6;

    float acc = 0.0f;
    #pragma unroll
    for (int r = 0; r < N / 1024; ++r) {   // 8 iterations
        int i = tid + r * 1024;
        float S = Spart[i] + Spart[N + i] + Spart[2 * N + i] + Spart[3 * N + i];
        acc += e[i] * (risk[i] - __logf(S + EPSV));
    }

    acc += __shfl_xor(acc, 32);
    acc += __shfl_xor(acc, 16);
    acc += __shfl_xor(acc, 8);
    acc += __shfl_xor(acc, 4);
    acc += __shfl_xor(acc, 2);
    acc += __shfl_xor(acc, 1);

    __shared__ float sW[16];
    if (lane == 0) sW[wave] = acc;
    __syncthreads();
    if (tid == 0) {
        float tot = 0.0f;
        #pragma unroll
        for (int x = 0; x < 16; ++x) tot += sW[x];
        out[0] = -tot * (1.0f / (float)N);
    }
}

extern "C" void kernel_launch(void* const* d_in, const int* in_sizes, int n_in,
                              void* d_out, int out_size, void* d_ws, size_t ws_size,
                              hipStream_t stream) {
    const float* risk = (const float*)d_in[0];
    const float* t    = (const float*)d_in[1];
    const float* e    = (const float*)d_in[2];
    float* out  = (float*)d_out;
    float* part = (float*)d_ws;   // NCHUNK * N floats = 128 KB of scratch

    dim3 grid(N / 32, NCHUNK);
    cox_partial<<<grid, BS, 0, stream>>>(risk, t, part);
    cox_final<<<1, 1024, 0, stream>>>(part, risk, e, out);
}